// Round 9
// baseline (390.245 us; speedup 1.0000x reference)
//
#include <hip/hip_runtime.h>
#include <hip/hip_bf16.h>
#include <math.h>

#define NN 50000
#define NE 800000
#define HD 128
#define SCAN_BLOCKS 196   // 196 * 256 = 50176 >= NN
#define FILL_CHUNK 4096   // edges per fill block
#define FILL_CHUNKS ((NE + FILL_CHUNK - 1) / FILL_CHUNK)   // 196
#define NPART 8           // dst partitions, pinned to XCDs via blockIdx&7

typedef __attribute__((ext_vector_type(8))) short bf16x8;
typedef __attribute__((ext_vector_type(4))) float f32x4;

__device__ inline float b2f(unsigned short s) {
    union { unsigned int u; float f; } w; w.u = ((unsigned int)s) << 16; return w.f;
}
__device__ inline short f2b(float f) {
    __hip_bfloat16 h = __float2bfloat16(f);
    short s; __builtin_memcpy(&s, &h, 2); return s;
}

// ---------------- CSR build ----------------
__global__ void hist_kernel(const int* __restrict__ dst, int* __restrict__ counts) {
    int e = blockIdx.x * blockDim.x + threadIdx.x;
    if (e < NE) atomicAdd(&counts[dst[e]], 1);
}

__global__ __launch_bounds__(256) void scan_partial_kernel(const int* __restrict__ counts,
                                                           int* __restrict__ partial) {
    __shared__ int sm[256];
    int i = blockIdx.x * 256 + threadIdx.x;
    sm[threadIdx.x] = (i < NN) ? counts[i] : 0;
    __syncthreads();
    for (int off = 128; off > 0; off >>= 1) {
        if (threadIdx.x < off) sm[threadIdx.x] += sm[threadIdx.x + off];
        __syncthreads();
    }
    if (threadIdx.x == 0) partial[blockIdx.x] = sm[0];
}

__global__ __launch_bounds__(256) void scan_base_kernel(const int* __restrict__ partial,
                                                        int* __restrict__ base) {
    __shared__ int sm[256];
    int tid = threadIdx.x;
    int v = (tid < SCAN_BLOCKS) ? partial[tid] : 0;
    sm[tid] = v;
    __syncthreads();
    for (int off = 1; off < 256; off <<= 1) {
        int t = (tid >= off) ? sm[tid - off] : 0;
        __syncthreads();
        sm[tid] += t;
        __syncthreads();
    }
    if (tid < SCAN_BLOCKS) base[tid] = sm[tid] - v;   // exclusive
}

__global__ __launch_bounds__(256) void scan_final_kernel(const int* __restrict__ counts,
                                                         const int* __restrict__ base,
                                                         int* __restrict__ offsets,
                                                         int* __restrict__ cursor) {
    __shared__ int sm[256];
    int tid = threadIdx.x;
    int i = blockIdx.x * 256 + tid;
    int v = (i < NN) ? counts[i] : 0;
    sm[tid] = v;
    __syncthreads();
    for (int off = 1; off < 256; off <<= 1) {
        int t = (tid >= off) ? sm[tid - off] : 0;
        __syncthreads();
        sm[tid] += t;
        __syncthreads();
    }
    if (i < NN) {
        int o = base[blockIdx.x] + sm[tid] - v;   // exclusive prefix
        offsets[i] = o;
        cursor[i]  = o;
        if (i == NN - 1) offsets[NN] = o + v;
    }
}

// XCD-partitioned fill (round-8 win: WRITE_SIZE 52MB -> partial-line amp killed)
__global__ __launch_bounds__(256) void fill_part_kernel(const int* __restrict__ src,
                                                        const int* __restrict__ dst,
                                                        int* __restrict__ cursor,
                                                        int* __restrict__ perm_src) {
    int part  = blockIdx.x & (NPART - 1);
    int chunk = blockIdx.x >> 3;
    int lo = part * (NN / NPART);
    int hi = (part == NPART - 1) ? NN : lo + (NN / NPART);
    int e0 = chunk * FILL_CHUNK;
    int e1 = min(e0 + FILL_CHUNK, NE);
    for (int e = e0 + threadIdx.x; e < e1; e += 256) {
        int d = dst[e];
        if (d >= lo && d < hi) {
            int pos = atomicAdd(&cursor[d], 1);
            perm_src[pos] = src[e];
        }
    }
}

// ---------------- weight pack: into per-lane MFMA B-fragment layout ----------------
__global__ void pack_all(const float* W_in, const float* W_msg0, const float* W_msg1,
                         const float* W_out, const float* wih0, const float* whh0,
                         const float* wih1, const float* whh1,
                         short* pWin, short* pWm0, short* pWm1, short* pWout,
                         short* pI0, short* pH0, short* pI1, short* pH1) {
    const float* src; short* dst; int JT; bool kmajor; int J;
    switch (blockIdx.y) {
        case 0: src = W_in;   dst = pWin;  JT = 8;  kmajor = true;  J = 128; break;
        case 1: src = W_msg0; dst = pWm0;  JT = 8;  kmajor = true;  J = 128; break;
        case 2: src = W_msg1; dst = pWm1;  JT = 8;  kmajor = true;  J = 128; break;
        case 3: src = W_out;  dst = pWout; JT = 2;  kmajor = true;  J = 32;  break;
        case 4: src = wih0;   dst = pI0;   JT = 24; kmajor = false; J = 384; break;
        case 5: src = whh0;   dst = pH0;   JT = 24; kmajor = false; J = 384; break;
        case 6: src = wih1;   dst = pI1;   JT = 24; kmajor = false; J = 384; break;
        default: src = whh1;  dst = pH1;   JT = 24; kmajor = false; J = 384; break;
    }
    int t = blockIdx.x * 256 + threadIdx.x;
    if (t >= JT * 4 * 64) return;
    int l = t & 63, ks = (t >> 6) & 3, jt = t >> 8;
    int j = jt * 16 + (l & 15);
    int k0 = ks * 32 + (l >> 4) * 8;
    bf16x8 tv;
    if (kmajor) {
        #pragma unroll
        for (int i = 0; i < 8; ++i) tv[i] = f2b(src[(k0 + i) * J + j]);
    } else {
        #pragma unroll
        for (int i = 0; i < 8; ++i) tv[i] = f2b(src[j * 128 + k0 + i]);
    }
    *reinterpret_cast<bf16x8*>(dst + t * 8) = tv;
}

// ---------------- skinny MFMA GEMM, jt-split across blockIdx.y ----------------
// NSPLIT blocks cover the same 128-row stripe; each handles JT/NSPLIT col-tiles.
template<int JT, int NSPLIT, bool RELU, bool AF32, bool OUTF32>
__global__ __launch_bounds__(256) void gemm_mfma(const void* __restrict__ Av,
                                                 const short* __restrict__ Bp,
                                                 const float* __restrict__ bias,
                                                 void* __restrict__ Cv) {
    int w = threadIdx.x >> 6;
    int l = threadIdx.x & 63;
    int r0 = blockIdx.x * 128 + w * 32;
    int lr = l & 15;
    int lk = (l >> 4) * 8;
    const int JPB = JT / NSPLIT;
    int jt0 = blockIdx.y * JPB;

    bf16x8 a[2][4];
    #pragma unroll
    for (int mt = 0; mt < 2; ++mt) {
        int row = r0 + mt * 16 + lr;
        if (row > NN - 1) row = NN - 1;
        #pragma unroll
        for (int ks = 0; ks < 4; ++ks) {
            if (AF32) {
                const float* ap = (const float*)Av + (size_t)row * HD + ks * 32 + lk;
                float4 v0 = *(const float4*)ap;
                float4 v1 = *(const float4*)(ap + 4);
                bf16x8 tv;
                tv[0] = f2b(v0.x); tv[1] = f2b(v0.y); tv[2] = f2b(v0.z); tv[3] = f2b(v0.w);
                tv[4] = f2b(v1.x); tv[5] = f2b(v1.y); tv[6] = f2b(v1.z); tv[7] = f2b(v1.w);
                a[mt][ks] = tv;
            } else {
                a[mt][ks] = *reinterpret_cast<const bf16x8*>((const short*)Av + (size_t)row * HD + ks * 32 + lk);
            }
        }
    }

    #pragma unroll
    for (int jj = 0; jj < JPB; ++jj) {
        int jt = jt0 + jj;
        f32x4 acc0 = {0.f, 0.f, 0.f, 0.f}, acc1 = {0.f, 0.f, 0.f, 0.f};
        const short* bp = Bp + ((jt * 4) * 64 + l) * 8;
        #pragma unroll
        for (int ks = 0; ks < 4; ++ks) {
            bf16x8 b = *reinterpret_cast<const bf16x8*>(bp + ks * 64 * 8);
            acc0 = __builtin_amdgcn_mfma_f32_16x16x32_bf16(a[0][ks], b, acc0, 0, 0, 0);
            acc1 = __builtin_amdgcn_mfma_f32_16x16x32_bf16(a[1][ks], b, acc1, 0, 0, 0);
        }
        int col = jt * 16 + lr;
        float bs = bias ? bias[col] : 0.f;
        #pragma unroll
        for (int mt = 0; mt < 2; ++mt) {
            f32x4 acc = mt ? acc1 : acc0;
            #pragma unroll
            for (int rg = 0; rg < 4; ++rg) {
                int row = r0 + mt * 16 + (l >> 4) * 4 + rg;
                if (row < NN) {
                    float v = acc[rg] + bs;
                    if (RELU) v = fmaxf(v, 0.f);
                    if (OUTF32) ((float*)Cv)[(size_t)row * (16 * JT) + col] = v;
                    else        ((short*)Cv)[(size_t)row * (16 * JT) + col] = f2b(v);
                }
            }
        }
    }
}

// ---------------- CSR aggregate (bf16 in, fp32 accum, bf16 out) ----------------
__global__ __launch_bounds__(256) void aggregate_bf16(const short* __restrict__ m,
                                                      const int* __restrict__ offsets,
                                                      const int* __restrict__ perm_src,
                                                      short* __restrict__ agg) {
    int node = blockIdx.x * 8 + (threadIdx.x >> 5);
    if (node >= NN) return;
    int q = (threadIdx.x & 31) * 4;
    int beg = offsets[node], end = offsets[node + 1];
    float a0 = 0.f, a1 = 0.f, a2 = 0.f, a3 = 0.f;
    int e = beg;
    for (; e + 2 <= end; e += 2) {
        int s0 = perm_src[e], s1 = perm_src[e + 1];
        ushort4 u0 = *reinterpret_cast<const ushort4*>(m + (size_t)s0 * HD + q);
        ushort4 u1 = *reinterpret_cast<const ushort4*>(m + (size_t)s1 * HD + q);
        a0 += b2f(u0.x) + b2f(u1.x);
        a1 += b2f(u0.y) + b2f(u1.y);
        a2 += b2f(u0.z) + b2f(u1.z);
        a3 += b2f(u0.w) + b2f(u1.w);
    }
    if (e < end) {
        ushort4 u = *reinterpret_cast<const ushort4*>(m + (size_t)perm_src[e] * HD + q);
        a0 += b2f(u.x); a1 += b2f(u.y); a2 += b2f(u.z); a3 += b2f(u.w);
    }
    ushort4 o;
    o.x = (unsigned short)f2b(a0); o.y = (unsigned short)f2b(a1);
    o.z = (unsigned short)f2b(a2); o.w = (unsigned short)f2b(a3);
    *reinterpret_cast<ushort4*>(agg + (size_t)node * HD + q) = o;
}

// ---------------- fused GRU via MFMA, jt-split across blockIdx.y ----------------
__global__ __launch_bounds__(256) void gru_mfma(const short* __restrict__ agg,
                                                const short* __restrict__ h,
                                                const short* __restrict__ BpI,
                                                const short* __restrict__ BpH,
                                                const float* __restrict__ bih,
                                                const float* __restrict__ bhh,
                                                short* __restrict__ hout) {
    int w = threadIdx.x >> 6;
    int l = threadIdx.x & 63;
    int r0 = blockIdx.x * 128 + w * 32;
    int lr = l & 15;
    int lk = (l >> 4) * 8;
    int jt0 = blockIdx.y * 4;   // 2-way split: jt 0..3 / 4..7

    bf16x8 aa[2][4], ah[2][4];
    #pragma unroll
    for (int mt = 0; mt < 2; ++mt) {
        int row = r0 + mt * 16 + lr;
        if (row > NN - 1) row = NN - 1;
        #pragma unroll
        for (int ks = 0; ks < 4; ++ks) {
            aa[mt][ks] = *reinterpret_cast<const bf16x8*>(agg + (size_t)row * HD + ks * 32 + lk);
            ah[mt][ks] = *reinterpret_cast<const bf16x8*>(h   + (size_t)row * HD + ks * 32 + lk);
        }
    }

    const f32x4 zero = {0.f, 0.f, 0.f, 0.f};
    #pragma unroll 1
    for (int jj = 0; jj < 4; ++jj) {
        int jt = jt0 + jj;
        f32x4 ir[2] = {zero, zero}, iz[2] = {zero, zero}, in_[2] = {zero, zero};
        f32x4 hr[2] = {zero, zero}, hz[2] = {zero, zero}, hn[2] = {zero, zero};
        #pragma unroll
        for (int ks = 0; ks < 4; ++ks) {
            const short* bi = BpI + ((jt * 4 + ks) * 64 + l) * 8;
            const short* bh = BpH + ((jt * 4 + ks) * 64 + l) * 8;
            bf16x8 bir = *reinterpret_cast<const bf16x8*>(bi);
            bf16x8 biz = *reinterpret_cast<const bf16x8*>(bi + 8 * 4 * 64 * 8);
            bf16x8 bin = *reinterpret_cast<const bf16x8*>(bi + 16 * 4 * 64 * 8);
            bf16x8 bhr = *reinterpret_cast<const bf16x8*>(bh);
            bf16x8 bhz = *reinterpret_cast<const bf16x8*>(bh + 8 * 4 * 64 * 8);
            bf16x8 bhn = *reinterpret_cast<const bf16x8*>(bh + 16 * 4 * 64 * 8);
            #pragma unroll
            for (int mt = 0; mt < 2; ++mt) {
                ir[mt]  = __builtin_amdgcn_mfma_f32_16x16x32_bf16(aa[mt][ks], bir, ir[mt],  0, 0, 0);
                iz[mt]  = __builtin_amdgcn_mfma_f32_16x16x32_bf16(aa[mt][ks], biz, iz[mt],  0, 0, 0);
                in_[mt] = __builtin_amdgcn_mfma_f32_16x16x32_bf16(aa[mt][ks], bin, in_[mt], 0, 0, 0);
                hr[mt]  = __builtin_amdgcn_mfma_f32_16x16x32_bf16(ah[mt][ks], bhr, hr[mt],  0, 0, 0);
                hz[mt]  = __builtin_amdgcn_mfma_f32_16x16x32_bf16(ah[mt][ks], bhz, hz[mt],  0, 0, 0);
                hn[mt]  = __builtin_amdgcn_mfma_f32_16x16x32_bf16(ah[mt][ks], bhn, hn[mt],  0, 0, 0);
            }
        }
        int col = jt * 16 + lr;
        float bir_ = bih[col], biz_ = bih[128 + col], bin_ = bih[256 + col];
        float bhr_ = bhh[col], bhz_ = bhh[128 + col], bhn_ = bhh[256 + col];
        #pragma unroll
        for (int mt = 0; mt < 2; ++mt) {
            #pragma unroll
            for (int rg = 0; rg < 4; ++rg) {
                int row = r0 + mt * 16 + (l >> 4) * 4 + rg;
                if (row < NN) {
                    float rr = 1.f / (1.f + __expf(-(ir[mt][rg] + bir_ + hr[mt][rg] + bhr_)));
                    float zz = 1.f / (1.f + __expf(-(iz[mt][rg] + biz_ + hz[mt][rg] + bhz_)));
                    float pre = in_[mt][rg] + bin_ + rr * (hn[mt][rg] + bhn_);
                    pre = fminf(fmaxf(pre, -20.f), 20.f);
                    float e2 = __expf(2.f * pre);
                    float nn_ = (e2 - 1.f) / (e2 + 1.f);
                    float hv = b2f((unsigned short)h[(size_t)row * HD + col]);
                    hout[(size_t)row * HD + col] = f2b((1.f - zz) * nn_ + zz * hv);
                }
            }
        }
    }
}

// ---------------- launch ----------------
extern "C" void kernel_launch(void* const* d_in, const int* in_sizes, int n_in,
                              void* d_out, int out_size, void* d_ws, size_t ws_size,
                              hipStream_t stream) {
    const float* x      = (const float*)d_in[0];
    const int*   eidx   = (const int*)d_in[1];
    const float* W_in   = (const float*)d_in[2];
    const float* b_in   = (const float*)d_in[3];
    const float* W_msg0 = (const float*)d_in[4];
    const float* wih0   = (const float*)d_in[5];
    const float* whh0   = (const float*)d_in[6];
    const float* bih0   = (const float*)d_in[7];
    const float* bhh0   = (const float*)d_in[8];
    const float* W_msg1 = (const float*)d_in[9];
    const float* wih1   = (const float*)d_in[10];
    const float* whh1   = (const float*)d_in[11];
    const float* bih1   = (const float*)d_in[12];
    const float* bhh1   = (const float*)d_in[13];
    const float* W_out  = (const float*)d_in[14];
    const float* b_out  = (const float*)d_in[15];
    float* out = (float*)d_out;

    const int* src = eidx;
    const int* dst = eidx + NE;

    char* ws = (char*)d_ws;
    size_t off = 0;
    auto alloc = [&](size_t bytes) {
        void* p = ws + off;
        off += (bytes + 255) & ~(size_t)255;
        return p;
    };
    short* bufA = (short*)alloc((size_t)NN * HD * 2);
    short* bufB = (short*)alloc((size_t)NN * HD * 2);
    short* bufC = (short*)alloc((size_t)NN * HD * 2);
    short* pWin  = (short*)alloc(8  * 4 * 64 * 8 * 2);
    short* pWm0  = (short*)alloc(8  * 4 * 64 * 8 * 2);
    short* pWm1  = (short*)alloc(8  * 4 * 64 * 8 * 2);
    short* pWout = (short*)alloc(2  * 4 * 64 * 8 * 2);
    short* pI0   = (short*)alloc(24 * 4 * 64 * 8 * 2);
    short* pH0   = (short*)alloc(24 * 4 * 64 * 8 * 2);
    short* pI1   = (short*)alloc(24 * 4 * 64 * 8 * 2);
    short* pH1   = (short*)alloc(24 * 4 * 64 * 8 * 2);
    int* counts  = (int*)alloc(NN * 4);
    int* offsets = (int*)alloc((NN + 1) * 4);
    int* cursor  = (int*)alloc(NN * 4);
    int* perm    = (int*)alloc(NE * 4);
    int* partial = (int*)alloc(SCAN_BLOCKS * 4);
    int* pbase   = (int*)alloc(SCAN_BLOCKS * 4);

    // CSR build (parallel scan + XCD-partitioned fill)
    hipMemsetAsync(counts, 0, NN * 4, stream);
    hist_kernel<<<(NE + 255) / 256, 256, 0, stream>>>(dst, counts);
    scan_partial_kernel<<<SCAN_BLOCKS, 256, 0, stream>>>(counts, partial);
    scan_base_kernel<<<1, 256, 0, stream>>>(partial, pbase);
    scan_final_kernel<<<SCAN_BLOCKS, 256, 0, stream>>>(counts, pbase, offsets, cursor);
    fill_part_kernel<<<NPART * FILL_CHUNKS, 256, 0, stream>>>(src, dst, cursor, perm);

    // weight packing
    pack_all<<<dim3(24, 8), 256, 0, stream>>>(W_in, W_msg0, W_msg1, W_out,
                                              wih0, whh0, wih1, whh1,
                                              pWin, pWm0, pWm1, pWout, pI0, pH0, pI1, pH1);

    int g = (NN + 127) / 128;   // 391
    dim3 g2(g, 2);              // jt-split grid: 782 blocks

    // h0 = relu(x @ W_in + b_in)   (fp32 A, bf16 out)
    gemm_mfma<8, 2, true, true, false><<<g2, 256, 0, stream>>>(x, pWin, b_in, bufA);

    // layer 0
    gemm_mfma<8, 2, false, false, false><<<g2, 256, 0, stream>>>(bufA, pWm0, nullptr, bufB);
    aggregate_bf16<<<(NN + 7) / 8, 256, 0, stream>>>(bufB, offsets, perm, bufC);
    gru_mfma<<<g2, 256, 0, stream>>>(bufC, bufA, pI0, pH0, bih0, bhh0, bufB);

    // layer 1
    gemm_mfma<8, 2, false, false, false><<<g2, 256, 0, stream>>>(bufB, pWm1, nullptr, bufA);
    aggregate_bf16<<<(NN + 7) / 8, 256, 0, stream>>>(bufA, offsets, perm, bufC);
    gru_mfma<<<g2, 256, 0, stream>>>(bufC, bufB, pI1, pH1, bih1, bhh1, bufA);

    // out = h @ W_out + b_out  (fp32 out)
    gemm_mfma<2, 1, false, false, true><<<dim3(g, 1), 256, 0, stream>>>(bufA, pWout, b_out, out);
}

// Round 11
// 387.709 us; speedup vs baseline: 1.0065x; 1.0065x over previous
//
#include <hip/hip_runtime.h>
#include <hip/hip_bf16.h>
#include <math.h>

#define NN 50000
#define NE 800000
#define HD 128
#define SCAN_BLOCKS 196   // 196 * 256 = 50176 >= NN
#define FILL_CHUNK 4096   // edges per fill block
#define FILL_CHUNKS ((NE + FILL_CHUNK - 1) / FILL_CHUNK)   // 196
#define NPART 8           // dst partitions, pinned to XCDs via blockIdx&7

typedef __attribute__((ext_vector_type(8))) short bf16x8;
typedef __attribute__((ext_vector_type(4))) float f32x4;

__device__ inline float b2f(unsigned short s) {
    union { unsigned int u; float f; } w; w.u = ((unsigned int)s) << 16; return w.f;
}
__device__ inline short f2b(float f) {
    __hip_bfloat16 h = __float2bfloat16(f);
    short s; __builtin_memcpy(&s, &h, 2); return s;
}

// ---------------- CSR build ----------------
__global__ void hist_kernel(const int* __restrict__ dst, int* __restrict__ counts) {
    int e = blockIdx.x * blockDim.x + threadIdx.x;
    if (e < NE) atomicAdd(&counts[dst[e]], 1);
}

__global__ __launch_bounds__(256) void scan_partial_kernel(const int* __restrict__ counts,
                                                           int* __restrict__ partial) {
    __shared__ int sm[256];
    int i = blockIdx.x * 256 + threadIdx.x;
    sm[threadIdx.x] = (i < NN) ? counts[i] : 0;
    __syncthreads();
    for (int off = 128; off > 0; off >>= 1) {
        if (threadIdx.x < off) sm[threadIdx.x] += sm[threadIdx.x + off];
        __syncthreads();
    }
    if (threadIdx.x == 0) partial[blockIdx.x] = sm[0];
}

__global__ __launch_bounds__(256) void scan_base_kernel(const int* __restrict__ partial,
                                                        int* __restrict__ base) {
    __shared__ int sm[256];
    int tid = threadIdx.x;
    int v = (tid < SCAN_BLOCKS) ? partial[tid] : 0;
    sm[tid] = v;
    __syncthreads();
    for (int off = 1; off < 256; off <<= 1) {
        int t = (tid >= off) ? sm[tid - off] : 0;
        __syncthreads();
        sm[tid] += t;
        __syncthreads();
    }
    if (tid < SCAN_BLOCKS) base[tid] = sm[tid] - v;   // exclusive
}

__global__ __launch_bounds__(256) void scan_final_kernel(const int* __restrict__ counts,
                                                         const int* __restrict__ base,
                                                         int* __restrict__ offsets,
                                                         int* __restrict__ cursor) {
    __shared__ int sm[256];
    int tid = threadIdx.x;
    int i = blockIdx.x * 256 + tid;
    int v = (i < NN) ? counts[i] : 0;
    sm[tid] = v;
    __syncthreads();
    for (int off = 1; off < 256; off <<= 1) {
        int t = (tid >= off) ? sm[tid - off] : 0;
        __syncthreads();
        sm[tid] += t;
        __syncthreads();
    }
    if (i < NN) {
        int o = base[blockIdx.x] + sm[tid] - v;   // exclusive prefix
        offsets[i] = o;
        cursor[i]  = o;
        if (i == NN - 1) offsets[NN] = o + v;
    }
}

// XCD-partitioned fill (round-8 win: partial-line write amp killed)
__global__ __launch_bounds__(256) void fill_part_kernel(const int* __restrict__ src,
                                                        const int* __restrict__ dst,
                                                        int* __restrict__ cursor,
                                                        int* __restrict__ perm_src) {
    int part  = blockIdx.x & (NPART - 1);
    int chunk = blockIdx.x >> 3;
    int lo = part * (NN / NPART);
    int hi = (part == NPART - 1) ? NN : lo + (NN / NPART);
    int e0 = chunk * FILL_CHUNK;
    int e1 = min(e0 + FILL_CHUNK, NE);
    for (int e = e0 + threadIdx.x; e < e1; e += 256) {
        int d = dst[e];
        if (d >= lo && d < hi) {
            int pos = atomicAdd(&cursor[d], 1);
            perm_src[pos] = src[e];
        }
    }
}

// ---------------- weight pack: into per-lane MFMA B-fragment layout ----------------
__global__ void pack_all(const float* W_in, const float* W_msg0, const float* W_msg1,
                         const float* W_out, const float* wih0, const float* whh0,
                         const float* wih1, const float* whh1,
                         short* pWin, short* pWm0, short* pWm1, short* pWout,
                         short* pI0, short* pH0, short* pI1, short* pH1) {
    const float* src; short* dst; int JT; bool kmajor; int J;
    switch (blockIdx.y) {
        case 0: src = W_in;   dst = pWin;  JT = 8;  kmajor = true;  J = 128; break;
        case 1: src = W_msg0; dst = pWm0;  JT = 8;  kmajor = true;  J = 128; break;
        case 2: src = W_msg1; dst = pWm1;  JT = 8;  kmajor = true;  J = 128; break;
        case 3: src = W_out;  dst = pWout; JT = 2;  kmajor = true;  J = 32;  break;
        case 4: src = wih0;   dst = pI0;   JT = 24; kmajor = false; J = 384; break;
        case 5: src = whh0;   dst = pH0;   JT = 24; kmajor = false; J = 384; break;
        case 6: src = wih1;   dst = pI1;   JT = 24; kmajor = false; J = 384; break;
        default: src = whh1;  dst = pH1;   JT = 24; kmajor = false; J = 384; break;
    }
    int t = blockIdx.x * 256 + threadIdx.x;
    if (t >= JT * 4 * 64) return;
    int l = t & 63, ks = (t >> 6) & 3, jt = t >> 8;
    int j = jt * 16 + (l & 15);
    int k0 = ks * 32 + (l >> 4) * 8;
    bf16x8 tv;
    if (kmajor) {
        #pragma unroll
        for (int i = 0; i < 8; ++i) tv[i] = f2b(src[(k0 + i) * J + j]);
    } else {
        #pragma unroll
        for (int i = 0; i < 8; ++i) tv[i] = f2b(src[j * 128 + k0 + i]);
    }
    *reinterpret_cast<bf16x8*>(dst + t * 8) = tv;
}

// ---------------- skinny MFMA GEMM (round-8 config: 2 M-tiles, all JT per block) ----------------
template<int JT, bool RELU, bool AF32, bool OUTF32>
__global__ __launch_bounds__(256) void gemm_mfma(const void* __restrict__ Av,
                                                 const short* __restrict__ Bp,
                                                 const float* __restrict__ bias,
                                                 void* __restrict__ Cv) {
    int w = threadIdx.x >> 6;
    int l = threadIdx.x & 63;
    int r0 = blockIdx.x * 128 + w * 32;
    int lr = l & 15;
    int lk = (l >> 4) * 8;

    bf16x8 a[2][4];
    #pragma unroll
    for (int mt = 0; mt < 2; ++mt) {
        int row = r0 + mt * 16 + lr;
        if (row > NN - 1) row = NN - 1;
        #pragma unroll
        for (int ks = 0; ks < 4; ++ks) {
            if (AF32) {
                const float* ap = (const float*)Av + (size_t)row * HD + ks * 32 + lk;
                float4 v0 = *(const float4*)ap;
                float4 v1 = *(const float4*)(ap + 4);
                bf16x8 tv;
                tv[0] = f2b(v0.x); tv[1] = f2b(v0.y); tv[2] = f2b(v0.z); tv[3] = f2b(v0.w);
                tv[4] = f2b(v1.x); tv[5] = f2b(v1.y); tv[6] = f2b(v1.z); tv[7] = f2b(v1.w);
                a[mt][ks] = tv;
            } else {
                a[mt][ks] = *reinterpret_cast<const bf16x8*>((const short*)Av + (size_t)row * HD + ks * 32 + lk);
            }
        }
    }

    #pragma unroll
    for (int jt = 0; jt < JT; ++jt) {
        f32x4 acc0 = {0.f, 0.f, 0.f, 0.f}, acc1 = {0.f, 0.f, 0.f, 0.f};
        const short* bp = Bp + ((jt * 4) * 64 + l) * 8;
        #pragma unroll
        for (int ks = 0; ks < 4; ++ks) {
            bf16x8 b = *reinterpret_cast<const bf16x8*>(bp + ks * 64 * 8);
            acc0 = __builtin_amdgcn_mfma_f32_16x16x32_bf16(a[0][ks], b, acc0, 0, 0, 0);
            acc1 = __builtin_amdgcn_mfma_f32_16x16x32_bf16(a[1][ks], b, acc1, 0, 0, 0);
        }
        int col = jt * 16 + lr;
        float bs = bias ? bias[col] : 0.f;
        #pragma unroll
        for (int mt = 0; mt < 2; ++mt) {
            f32x4 acc = mt ? acc1 : acc0;
            #pragma unroll
            for (int rg = 0; rg < 4; ++rg) {
                int row = r0 + mt * 16 + (l >> 4) * 4 + rg;
                if (row < NN) {
                    float v = acc[rg] + bs;
                    if (RELU) v = fmaxf(v, 0.f);
                    if (OUTF32) ((float*)Cv)[(size_t)row * (16 * JT) + col] = v;
                    else        ((short*)Cv)[(size_t)row * (16 * JT) + col] = f2b(v);
                }
            }
        }
    }
}

// ---------------- CSR aggregate (bf16 in, fp32 accum, bf16 out) ----------------
__global__ __launch_bounds__(256) void aggregate_bf16(const short* __restrict__ m,
                                                      const int* __restrict__ offsets,
                                                      const int* __restrict__ perm_src,
                                                      short* __restrict__ agg) {
    int node = blockIdx.x * 8 + (threadIdx.x >> 5);
    if (node >= NN) return;
    int q = (threadIdx.x & 31) * 4;
    int beg = offsets[node], end = offsets[node + 1];
    float a0 = 0.f, a1 = 0.f, a2 = 0.f, a3 = 0.f;
    int e = beg;
    for (; e + 2 <= end; e += 2) {
        int s0 = perm_src[e], s1 = perm_src[e + 1];
        ushort4 u0 = *reinterpret_cast<const ushort4*>(m + (size_t)s0 * HD + q);
        ushort4 u1 = *reinterpret_cast<const ushort4*>(m + (size_t)s1 * HD + q);
        a0 += b2f(u0.x) + b2f(u1.x);
        a1 += b2f(u0.y) + b2f(u1.y);
        a2 += b2f(u0.z) + b2f(u1.z);
        a3 += b2f(u0.w) + b2f(u1.w);
    }
    if (e < end) {
        ushort4 u = *reinterpret_cast<const ushort4*>(m + (size_t)perm_src[e] * HD + q);
        a0 += b2f(u.x); a1 += b2f(u.y); a2 += b2f(u.z); a3 += b2f(u.w);
    }
    ushort4 o;
    o.x = (unsigned short)f2b(a0); o.y = (unsigned short)f2b(a1);
    o.z = (unsigned short)f2b(a2); o.w = (unsigned short)f2b(a3);
    *reinterpret_cast<ushort4*>(agg + (size_t)node * HD + q) = o;
}

// ---------------- fused GRU via MFMA: 16 rows/wave (mt=1), low register pressure ----------------
// Live state ~120 VGPR: 8 A-frags (32) + 12 accum f32x4 (48) + 6 B-frags (24) -> no spills.
__global__ __launch_bounds__(256) void gru_mfma(const short* __restrict__ agg,
                                                const short* __restrict__ h,
                                                const short* __restrict__ BpI,
                                                const short* __restrict__ BpH,
                                                const float* __restrict__ bih,
                                                const float* __restrict__ bhh,
                                                short* __restrict__ hout) {
    int w = threadIdx.x >> 6;
    int l = threadIdx.x & 63;
    int r0 = blockIdx.x * 64 + w * 16;   // 16 rows per wave
    int lr = l & 15;
    int lk = (l >> 4) * 8;

    bf16x8 aa[4], ah[4];
    {
        int row = r0 + lr;
        if (row > NN - 1) row = NN - 1;
        #pragma unroll
        for (int ks = 0; ks < 4; ++ks) {
            aa[ks] = *reinterpret_cast<const bf16x8*>(agg + (size_t)row * HD + ks * 32 + lk);
            ah[ks] = *reinterpret_cast<const bf16x8*>(h   + (size_t)row * HD + ks * 32 + lk);
        }
    }

    const f32x4 zero = {0.f, 0.f, 0.f, 0.f};
    #pragma unroll 1
    for (int jt = 0; jt < 8; ++jt) {
        f32x4 ir = zero, iz = zero, in_ = zero;
        f32x4 hr = zero, hz = zero, hn = zero;
        #pragma unroll
        for (int ks = 0; ks < 4; ++ks) {
            const short* bi = BpI + ((jt * 4 + ks) * 64 + l) * 8;
            const short* bh = BpH + ((jt * 4 + ks) * 64 + l) * 8;
            bf16x8 bir = *reinterpret_cast<const bf16x8*>(bi);
            bf16x8 biz = *reinterpret_cast<const bf16x8*>(bi + 8 * 4 * 64 * 8);
            bf16x8 bin = *reinterpret_cast<const bf16x8*>(bi + 16 * 4 * 64 * 8);
            bf16x8 bhr = *reinterpret_cast<const bf16x8*>(bh);
            bf16x8 bhz = *reinterpret_cast<const bf16x8*>(bh + 8 * 4 * 64 * 8);
            bf16x8 bhn = *reinterpret_cast<const bf16x8*>(bh + 16 * 4 * 64 * 8);
            ir  = __builtin_amdgcn_mfma_f32_16x16x32_bf16(aa[ks], bir, ir,  0, 0, 0);
            iz  = __builtin_amdgcn_mfma_f32_16x16x32_bf16(aa[ks], biz, iz,  0, 0, 0);
            in_ = __builtin_amdgcn_mfma_f32_16x16x32_bf16(aa[ks], bin, in_, 0, 0, 0);
            hr  = __builtin_amdgcn_mfma_f32_16x16x32_bf16(ah[ks], bhr, hr,  0, 0, 0);
            hz  = __builtin_amdgcn_mfma_f32_16x16x32_bf16(ah[ks], bhz, hz,  0, 0, 0);
            hn  = __builtin_amdgcn_mfma_f32_16x16x32_bf16(ah[ks], bhn, hn,  0, 0, 0);
        }
        int col = jt * 16 + lr;
        float bir_ = bih[col], biz_ = bih[128 + col], bin_ = bih[256 + col];
        float bhr_ = bhh[col], bhz_ = bhh[128 + col], bhn_ = bhh[256 + col];
        #pragma unroll
        for (int rg = 0; rg < 4; ++rg) {
            int row = r0 + (l >> 4) * 4 + rg;
            if (row < NN) {
                float rr = 1.f / (1.f + __expf(-(ir[rg] + bir_ + hr[rg] + bhr_)));
                float zz = 1.f / (1.f + __expf(-(iz[rg] + biz_ + hz[rg] + bhz_)));
                float pre = in_[rg] + bin_ + rr * (hn[rg] + bhn_);
                pre = fminf(fmaxf(pre, -20.f), 20.f);
                float e2 = __expf(2.f * pre);
                float nn_ = (e2 - 1.f) / (e2 + 1.f);
                float hv = b2f((unsigned short)h[(size_t)row * HD + col]);
                hout[(size_t)row * HD + col] = f2b((1.f - zz) * nn_ + zz * hv);
            }
        }
    }
}

// ---------------- launch ----------------
extern "C" void kernel_launch(void* const* d_in, const int* in_sizes, int n_in,
                              void* d_out, int out_size, void* d_ws, size_t ws_size,
                              hipStream_t stream) {
    const float* x      = (const float*)d_in[0];
    const int*   eidx   = (const int*)d_in[1];
    const float* W_in   = (const float*)d_in[2];
    const float* b_in   = (const float*)d_in[3];
    const float* W_msg0 = (const float*)d_in[4];
    const float* wih0   = (const float*)d_in[5];
    const float* whh0   = (const float*)d_in[6];
    const float* bih0   = (const float*)d_in[7];
    const float* bhh0   = (const float*)d_in[8];
    const float* W_msg1 = (const float*)d_in[9];
    const float* wih1   = (const float*)d_in[10];
    const float* whh1   = (const float*)d_in[11];
    const float* bih1   = (const float*)d_in[12];
    const float* bhh1   = (const float*)d_in[13];
    const float* W_out  = (const float*)d_in[14];
    const float* b_out  = (const float*)d_in[15];
    float* out = (float*)d_out;

    const int* src = eidx;
    const int* dst = eidx + NE;

    char* ws = (char*)d_ws;
    size_t off = 0;
    auto alloc = [&](size_t bytes) {
        void* p = ws + off;
        off += (bytes + 255) & ~(size_t)255;
        return p;
    };
    short* bufA = (short*)alloc((size_t)NN * HD * 2);
    short* bufB = (short*)alloc((size_t)NN * HD * 2);
    short* bufC = (short*)alloc((size_t)NN * HD * 2);
    short* pWin  = (short*)alloc(8  * 4 * 64 * 8 * 2);
    short* pWm0  = (short*)alloc(8  * 4 * 64 * 8 * 2);
    short* pWm1  = (short*)alloc(8  * 4 * 64 * 8 * 2);
    short* pWout = (short*)alloc(2  * 4 * 64 * 8 * 2);
    short* pI0   = (short*)alloc(24 * 4 * 64 * 8 * 2);
    short* pH0   = (short*)alloc(24 * 4 * 64 * 8 * 2);
    short* pI1   = (short*)alloc(24 * 4 * 64 * 8 * 2);
    short* pH1   = (short*)alloc(24 * 4 * 64 * 8 * 2);
    int* counts  = (int*)alloc(NN * 4);
    int* offsets = (int*)alloc((NN + 1) * 4);
    int* cursor  = (int*)alloc(NN * 4);
    int* perm    = (int*)alloc(NE * 4);
    int* partial = (int*)alloc(SCAN_BLOCKS * 4);
    int* pbase   = (int*)alloc(SCAN_BLOCKS * 4);

    // CSR build (parallel scan + XCD-partitioned fill)
    hipMemsetAsync(counts, 0, NN * 4, stream);
    hist_kernel<<<(NE + 255) / 256, 256, 0, stream>>>(dst, counts);
    scan_partial_kernel<<<SCAN_BLOCKS, 256, 0, stream>>>(counts, partial);
    scan_base_kernel<<<1, 256, 0, stream>>>(partial, pbase);
    scan_final_kernel<<<SCAN_BLOCKS, 256, 0, stream>>>(counts, pbase, offsets, cursor);
    fill_part_kernel<<<NPART * FILL_CHUNKS, 256, 0, stream>>>(src, dst, cursor, perm);

    // weight packing
    pack_all<<<dim3(24, 8), 256, 0, stream>>>(W_in, W_msg0, W_msg1, W_out,
                                              wih0, whh0, wih1, whh1,
                                              pWin, pWm0, pWm1, pWout, pI0, pH0, pI1, pH1);

    int g   = (NN + 127) / 128;  // 391 (gemm: 128 rows/block)
    int g64 = (NN + 63) / 64;    // 782 (gru: 64 rows/block)

    // h0 = relu(x @ W_in + b_in)   (fp32 A, bf16 out)
    gemm_mfma<8, true, true, false><<<g, 256, 0, stream>>>(x, pWin, b_in, bufA);

    // layer 0
    gemm_mfma<8, false, false, false><<<g, 256, 0, stream>>>(bufA, pWm0, nullptr, bufB);
    aggregate_bf16<<<(NN + 7) / 8, 256, 0, stream>>>(bufB, offsets, perm, bufC);
    gru_mfma<<<g64, 256, 0, stream>>>(bufC, bufA, pI0, pH0, bih0, bhh0, bufB);

    // layer 1
    gemm_mfma<8, false, false, false><<<g, 256, 0, stream>>>(bufB, pWm1, nullptr, bufA);
    aggregate_bf16<<<(NN + 7) / 8, 256, 0, stream>>>(bufA, offsets, perm, bufC);
    gru_mfma<<<g64, 256, 0, stream>>>(bufC, bufB, pI1, pH1, bih1, bhh1, bufA);

    // out = h @ W_out + b_out  (fp32 out)
    gemm_mfma<2, false, false, true><<<g, 256, 0, stream>>>(bufA, pWout, b_out, out);
}

// Round 12
// 360.222 us; speedup vs baseline: 1.0833x; 1.0763x over previous
//
#include <hip/hip_runtime.h>
#include <hip/hip_bf16.h>
#include <math.h>

#define NN 50000
#define NE 800000
#define HD 128
#define SCAN_BLOCKS 196   // 196 * 256 = 50176 >= NN
#define FILL_CHUNK 4096
#define FILL_CHUNKS ((NE + FILL_CHUNK - 1) / FILL_CHUNK)   // 196
#define NPART 8
#define HIST_BLOCKS ((NE + 255) / 256)   // 3125

typedef __attribute__((ext_vector_type(8))) short bf16x8;
typedef __attribute__((ext_vector_type(4))) float f32x4;

__device__ inline float b2f(unsigned short s) {
    union { unsigned int u; float f; } w; w.u = ((unsigned int)s) << 16; return w.f;
}
__device__ inline short f2b(float f) {
    __hip_bfloat16 h = __float2bfloat16(f);
    short s; __builtin_memcpy(&s, &h, 2); return s;
}

// ---------------- prep: hist + weight pack fused (independent work, one launch) ----------------
__global__ void prep_kernel(const int* __restrict__ dst, int* __restrict__ counts,
                            const float* W_in, const float* W_msg0, const float* W_msg1,
                            const float* W_out, const float* wih0, const float* whh0,
                            const float* wih1, const float* whh1,
                            short* pWin, short* pWm0, short* pWm1, short* pWout,
                            short* pI0, short* pH0, short* pI1, short* pH1) {
    int b = blockIdx.x;
    if (b < HIST_BLOCKS) {
        int e = b * 256 + threadIdx.x;
        if (e < NE) atomicAdd(&counts[dst[e]], 1);
        return;
    }
    int pb = b - HIST_BLOCKS;       // 0..191
    int px = pb % 24, wsel = pb / 24;
    const float* src; short* dstp; int JT; bool kmajor; int J;
    switch (wsel) {
        case 0: src = W_in;   dstp = pWin;  JT = 8;  kmajor = true;  J = 128; break;
        case 1: src = W_msg0; dstp = pWm0;  JT = 8;  kmajor = true;  J = 128; break;
        case 2: src = W_msg1; dstp = pWm1;  JT = 8;  kmajor = true;  J = 128; break;
        case 3: src = W_out;  dstp = pWout; JT = 2;  kmajor = true;  J = 32;  break;
        case 4: src = wih0;   dstp = pI0;   JT = 24; kmajor = false; J = 384; break;
        case 5: src = whh0;   dstp = pH0;   JT = 24; kmajor = false; J = 384; break;
        case 6: src = wih1;   dstp = pI1;   JT = 24; kmajor = false; J = 384; break;
        default: src = whh1;  dstp = pH1;   JT = 24; kmajor = false; J = 384; break;
    }
    int t = px * 256 + threadIdx.x;
    if (t >= JT * 4 * 64) return;
    int l = t & 63, ks = (t >> 6) & 3, jt = t >> 8;
    int j = jt * 16 + (l & 15);
    int k0 = ks * 32 + (l >> 4) * 8;
    bf16x8 tv;
    if (kmajor) {
        #pragma unroll
        for (int i = 0; i < 8; ++i) tv[i] = f2b(src[(k0 + i) * J + j]);
    } else {
        #pragma unroll
        for (int i = 0; i < 8; ++i) tv[i] = f2b(src[j * 128 + k0 + i]);
    }
    *reinterpret_cast<bf16x8*>(dstp + t * 8) = tv;
}

// ---------------- scan (3-stage device-wide) ----------------
__global__ __launch_bounds__(256) void scan_partial_kernel(const int* __restrict__ counts,
                                                           int* __restrict__ partial) {
    __shared__ int sm[256];
    int i = blockIdx.x * 256 + threadIdx.x;
    sm[threadIdx.x] = (i < NN) ? counts[i] : 0;
    __syncthreads();
    for (int off = 128; off > 0; off >>= 1) {
        if (threadIdx.x < off) sm[threadIdx.x] += sm[threadIdx.x + off];
        __syncthreads();
    }
    if (threadIdx.x == 0) partial[blockIdx.x] = sm[0];
}

__global__ __launch_bounds__(256) void scan_base_kernel(const int* __restrict__ partial,
                                                        int* __restrict__ base) {
    __shared__ int sm[256];
    int tid = threadIdx.x;
    int v = (tid < SCAN_BLOCKS) ? partial[tid] : 0;
    sm[tid] = v;
    __syncthreads();
    for (int off = 1; off < 256; off <<= 1) {
        int t = (tid >= off) ? sm[tid - off] : 0;
        __syncthreads();
        sm[tid] += t;
        __syncthreads();
    }
    if (tid < SCAN_BLOCKS) base[tid] = sm[tid] - v;
}

__global__ __launch_bounds__(256) void scan_final_kernel(const int* __restrict__ counts,
                                                         const int* __restrict__ base,
                                                         int* __restrict__ offsets,
                                                         int* __restrict__ cursor) {
    __shared__ int sm[256];
    int tid = threadIdx.x;
    int i = blockIdx.x * 256 + tid;
    int v = (i < NN) ? counts[i] : 0;
    sm[tid] = v;
    __syncthreads();
    for (int off = 1; off < 256; off <<= 1) {
        int t = (tid >= off) ? sm[tid - off] : 0;
        __syncthreads();
        sm[tid] += t;
        __syncthreads();
    }
    if (i < NN) {
        int o = base[blockIdx.x] + sm[tid] - v;
        offsets[i] = o;
        cursor[i]  = o;
        if (i == NN - 1) offsets[NN] = o + v;
    }
}

// XCD-partitioned fill (round-8 win)
__global__ __launch_bounds__(256) void fill_part_kernel(const int* __restrict__ src,
                                                        const int* __restrict__ dst,
                                                        int* __restrict__ cursor,
                                                        int* __restrict__ perm_src) {
    int part  = blockIdx.x & (NPART - 1);
    int chunk = blockIdx.x >> 3;
    int lo = part * (NN / NPART);
    int hi = (part == NPART - 1) ? NN : lo + (NN / NPART);
    int e0 = chunk * FILL_CHUNK;
    int e1 = min(e0 + FILL_CHUNK, NE);
    for (int e = e0 + threadIdx.x; e < e1; e += 256) {
        int d = dst[e];
        if (d >= lo && d < hi) {
            int pos = atomicAdd(&cursor[d], 1);
            perm_src[pos] = src[e];
        }
    }
}

// ---------------- CSR aggregate (bf16 in, fp32 accum, bf16 out) ----------------
__global__ __launch_bounds__(256) void aggregate_bf16(const short* __restrict__ m,
                                                      const int* __restrict__ offsets,
                                                      const int* __restrict__ perm_src,
                                                      short* __restrict__ agg) {
    int node = blockIdx.x * 8 + (threadIdx.x >> 5);
    if (node >= NN) return;
    int q = (threadIdx.x & 31) * 4;
    int beg = offsets[node], end = offsets[node + 1];
    float a0 = 0.f, a1 = 0.f, a2 = 0.f, a3 = 0.f;
    int e = beg;
    for (; e + 2 <= end; e += 2) {
        int s0 = perm_src[e], s1 = perm_src[e + 1];
        ushort4 u0 = *reinterpret_cast<const ushort4*>(m + (size_t)s0 * HD + q);
        ushort4 u1 = *reinterpret_cast<const ushort4*>(m + (size_t)s1 * HD + q);
        a0 += b2f(u0.x) + b2f(u1.x);
        a1 += b2f(u0.y) + b2f(u1.y);
        a2 += b2f(u0.z) + b2f(u1.z);
        a3 += b2f(u0.w) + b2f(u1.w);
    }
    if (e < end) {
        ushort4 u = *reinterpret_cast<const ushort4*>(m + (size_t)perm_src[e] * HD + q);
        a0 += b2f(u.x); a1 += b2f(u.y); a2 += b2f(u.z); a3 += b2f(u.w);
    }
    ushort4 o;
    o.x = (unsigned short)f2b(a0); o.y = (unsigned short)f2b(a1);
    o.z = (unsigned short)f2b(a2); o.w = (unsigned short)f2b(a3);
    *reinterpret_cast<ushort4*>(agg + (size_t)node * HD + q) = o;
}

// ---------------- shared phase-2: C2 = hLDS @ Bp2 (+bias2) ----------------
// LDS tile per wave: [16][128] bf16, col XOR-swizzled with ((row&7)<<3) (elem units).
template<int JT2, bool OUTF32_2>
__device__ inline void second_gemm(const short* hw, int l, int r0,
                                   const short* __restrict__ Bp2,
                                   const float* __restrict__ bias2,
                                   void* __restrict__ Cv2) {
    int lr = l & 15;
    bf16x8 a2[4];
    #pragma unroll
    for (int ks = 0; ks < 4; ++ks) {
        int row = l & 15;
        int col = (ks * 32 + (l >> 4) * 8) ^ ((row & 7) << 3);
        a2[ks] = *reinterpret_cast<const bf16x8*>(hw + row * 128 + col);
    }
    const f32x4 zero = {0.f, 0.f, 0.f, 0.f};
    #pragma unroll
    for (int jt = 0; jt < JT2; ++jt) {
        f32x4 acc = zero;
        const short* bp = Bp2 + ((jt * 4) * 64 + l) * 8;
        #pragma unroll
        for (int ks = 0; ks < 4; ++ks) {
            bf16x8 b = *reinterpret_cast<const bf16x8*>(bp + ks * 64 * 8);
            acc = __builtin_amdgcn_mfma_f32_16x16x32_bf16(a2[ks], b, acc, 0, 0, 0);
        }
        int col = jt * 16 + lr;
        float bs = bias2 ? bias2[col] : 0.f;
        #pragma unroll
        for (int rg = 0; rg < 4; ++rg) {
            int row = r0 + (l >> 4) * 4 + rg;
            if (row < NN) {
                float v = acc[rg] + bs;
                if (OUTF32_2) ((float*)Cv2)[(size_t)row * (16 * JT2) + col] = v;
                else          ((short*)Cv2)[(size_t)row * (16 * JT2) + col] = f2b(v);
            }
        }
    }
}

// ---------------- fused: h0 = relu(x @ W_in + b), m0 = h0 @ W_msg0 ----------------
__global__ __launch_bounds__(256) void fused_in_msg(const float* __restrict__ x,
                                                    const short* __restrict__ Bp1,
                                                    const float* __restrict__ bias1,
                                                    const short* __restrict__ Bp2,
                                                    short* __restrict__ Hout,
                                                    short* __restrict__ Mout) {
    __shared__ short hl[4][2048];
    int w = threadIdx.x >> 6, l = threadIdx.x & 63;
    int r0 = blockIdx.x * 64 + w * 16;
    int lr = l & 15, lk = (l >> 4) * 8;
    short* hw = hl[w];

    bf16x8 a[4];
    {
        int row = min(r0 + lr, NN - 1);
        #pragma unroll
        for (int ks = 0; ks < 4; ++ks) {
            const float* ap = x + (size_t)row * HD + ks * 32 + lk;
            float4 v0 = *(const float4*)ap;
            float4 v1 = *(const float4*)(ap + 4);
            bf16x8 tv;
            tv[0] = f2b(v0.x); tv[1] = f2b(v0.y); tv[2] = f2b(v0.z); tv[3] = f2b(v0.w);
            tv[4] = f2b(v1.x); tv[5] = f2b(v1.y); tv[6] = f2b(v1.z); tv[7] = f2b(v1.w);
            a[ks] = tv;
        }
    }

    const f32x4 zero = {0.f, 0.f, 0.f, 0.f};
    #pragma unroll
    for (int jt = 0; jt < 8; ++jt) {
        f32x4 acc = zero;
        const short* bp = Bp1 + ((jt * 4) * 64 + l) * 8;
        #pragma unroll
        for (int ks = 0; ks < 4; ++ks) {
            bf16x8 b = *reinterpret_cast<const bf16x8*>(bp + ks * 64 * 8);
            acc = __builtin_amdgcn_mfma_f32_16x16x32_bf16(a[ks], b, acc, 0, 0, 0);
        }
        int col = jt * 16 + lr;
        float bs = bias1[col];
        #pragma unroll
        for (int rg = 0; rg < 4; ++rg) {
            int row16 = (l >> 4) * 4 + rg;
            int grow = r0 + row16;
            float v = fmaxf(acc[rg] + bs, 0.f);
            short hb = f2b(v);
            hw[row16 * 128 + (col ^ ((row16 & 7) << 3))] = hb;
            if (grow < NN) Hout[(size_t)grow * HD + col] = hb;
        }
    }
    __syncthreads();
    second_gemm<8, false>(hw, l, r0, Bp2, nullptr, Mout);
}

// ---------------- fused: h' = GRU(agg,h), C2 = h' @ Bp2 (+bias2) ----------------
template<int JT2, bool OUTF32_2, bool WRITE_H>
__global__ __launch_bounds__(256) void fused_gru(const short* __restrict__ agg,
                                                 const short* __restrict__ h,
                                                 const short* __restrict__ BpI,
                                                 const short* __restrict__ BpH,
                                                 const float* __restrict__ bih,
                                                 const float* __restrict__ bhh,
                                                 const short* __restrict__ Bp2,
                                                 const float* __restrict__ bias2,
                                                 short* __restrict__ Hout,
                                                 void* __restrict__ Cv2) {
    __shared__ short hl[4][2048];
    int w = threadIdx.x >> 6, l = threadIdx.x & 63;
    int r0 = blockIdx.x * 64 + w * 16;
    int lr = l & 15, lk = (l >> 4) * 8;
    short* hw = hl[w];

    bf16x8 aa[4], ah[4];
    {
        int row = min(r0 + lr, NN - 1);
        #pragma unroll
        for (int ks = 0; ks < 4; ++ks) {
            aa[ks] = *reinterpret_cast<const bf16x8*>(agg + (size_t)row * HD + ks * 32 + lk);
            ah[ks] = *reinterpret_cast<const bf16x8*>(h   + (size_t)row * HD + ks * 32 + lk);
        }
    }

    const f32x4 zero = {0.f, 0.f, 0.f, 0.f};
    #pragma unroll 1
    for (int jt = 0; jt < 8; ++jt) {
        f32x4 ir = zero, iz = zero, in_ = zero;
        f32x4 hr = zero, hz = zero, hn = zero;
        #pragma unroll
        for (int ks = 0; ks < 4; ++ks) {
            const short* bi = BpI + ((jt * 4 + ks) * 64 + l) * 8;
            const short* bh = BpH + ((jt * 4 + ks) * 64 + l) * 8;
            bf16x8 bir = *reinterpret_cast<const bf16x8*>(bi);
            bf16x8 biz = *reinterpret_cast<const bf16x8*>(bi + 8 * 4 * 64 * 8);
            bf16x8 bin = *reinterpret_cast<const bf16x8*>(bi + 16 * 4 * 64 * 8);
            bf16x8 bhr = *reinterpret_cast<const bf16x8*>(bh);
            bf16x8 bhz = *reinterpret_cast<const bf16x8*>(bh + 8 * 4 * 64 * 8);
            bf16x8 bhn = *reinterpret_cast<const bf16x8*>(bh + 16 * 4 * 64 * 8);
            ir  = __builtin_amdgcn_mfma_f32_16x16x32_bf16(aa[ks], bir, ir,  0, 0, 0);
            iz  = __builtin_amdgcn_mfma_f32_16x16x32_bf16(aa[ks], biz, iz,  0, 0, 0);
            in_ = __builtin_amdgcn_mfma_f32_16x16x32_bf16(aa[ks], bin, in_, 0, 0, 0);
            hr  = __builtin_amdgcn_mfma_f32_16x16x32_bf16(ah[ks], bhr, hr,  0, 0, 0);
            hz  = __builtin_amdgcn_mfma_f32_16x16x32_bf16(ah[ks], bhz, hz,  0, 0, 0);
            hn  = __builtin_amdgcn_mfma_f32_16x16x32_bf16(ah[ks], bhn, hn,  0, 0, 0);
        }
        int col = jt * 16 + lr;
        float bir_ = bih[col], biz_ = bih[128 + col], bin_ = bih[256 + col];
        float bhr_ = bhh[col], bhz_ = bhh[128 + col], bhn_ = bhh[256 + col];
        #pragma unroll
        for (int rg = 0; rg < 4; ++rg) {
            int row16 = (l >> 4) * 4 + rg;
            int grow = r0 + row16;
            int crow = min(grow, NN - 1);
            float rr = 1.f / (1.f + __expf(-(ir[rg] + bir_ + hr[rg] + bhr_)));
            float zz = 1.f / (1.f + __expf(-(iz[rg] + biz_ + hz[rg] + bhz_)));
            float pre = in_[rg] + bin_ + rr * (hn[rg] + bhn_);
            pre = fminf(fmaxf(pre, -20.f), 20.f);
            float e2 = __expf(2.f * pre);
            float nn_ = (e2 - 1.f) / (e2 + 1.f);
            float hv = b2f((unsigned short)h[(size_t)crow * HD + col]);
            float nh = (1.f - zz) * nn_ + zz * hv;
            short hb = f2b(nh);
            hw[row16 * 128 + (col ^ ((row16 & 7) << 3))] = hb;
            if (WRITE_H && grow < NN) Hout[(size_t)grow * HD + col] = hb;
        }
    }
    __syncthreads();
    second_gemm<JT2, OUTF32_2>(hw, l, r0, Bp2, bias2, Cv2);
}

// ---------------- launch ----------------
extern "C" void kernel_launch(void* const* d_in, const int* in_sizes, int n_in,
                              void* d_out, int out_size, void* d_ws, size_t ws_size,
                              hipStream_t stream) {
    const float* x      = (const float*)d_in[0];
    const int*   eidx   = (const int*)d_in[1];
    const float* W_in   = (const float*)d_in[2];
    const float* b_in   = (const float*)d_in[3];
    const float* W_msg0 = (const float*)d_in[4];
    const float* wih0   = (const float*)d_in[5];
    const float* whh0   = (const float*)d_in[6];
    const float* bih0   = (const float*)d_in[7];
    const float* bhh0   = (const float*)d_in[8];
    const float* W_msg1 = (const float*)d_in[9];
    const float* wih1   = (const float*)d_in[10];
    const float* whh1   = (const float*)d_in[11];
    const float* bih1   = (const float*)d_in[12];
    const float* bhh1   = (const float*)d_in[13];
    const float* W_out  = (const float*)d_in[14];
    const float* b_out  = (const float*)d_in[15];
    float* out = (float*)d_out;

    const int* src = eidx;
    const int* dst = eidx + NE;

    char* ws = (char*)d_ws;
    size_t off = 0;
    auto alloc = [&](size_t bytes) {
        void* p = ws + off;
        off += (bytes + 255) & ~(size_t)255;
        return p;
    };
    short* bufA = (short*)alloc((size_t)NN * HD * 2);   // h0, then m1
    short* bufB = (short*)alloc((size_t)NN * HD * 2);   // m0, then h1
    short* bufC = (short*)alloc((size_t)NN * HD * 2);   // agg0 / agg1
    short* pWin  = (short*)alloc(8  * 4 * 64 * 8 * 2);
    short* pWm0  = (short*)alloc(8  * 4 * 64 * 8 * 2);
    short* pWm1  = (short*)alloc(8  * 4 * 64 * 8 * 2);
    short* pWout = (short*)alloc(2  * 4 * 64 * 8 * 2);
    short* pI0   = (short*)alloc(24 * 4 * 64 * 8 * 2);
    short* pH0   = (short*)alloc(24 * 4 * 64 * 8 * 2);
    short* pI1   = (short*)alloc(24 * 4 * 64 * 8 * 2);
    short* pH1   = (short*)alloc(24 * 4 * 64 * 8 * 2);
    int* counts  = (int*)alloc(NN * 4);
    int* offsets = (int*)alloc((NN + 1) * 4);
    int* cursor  = (int*)alloc(NN * 4);
    int* perm    = (int*)alloc(NE * 4);
    int* partial = (int*)alloc(SCAN_BLOCKS * 4);
    int* pbase   = (int*)alloc(SCAN_BLOCKS * 4);

    // CSR build + weight pack
    hipMemsetAsync(counts, 0, NN * 4, stream);
    prep_kernel<<<HIST_BLOCKS + 192, 256, 0, stream>>>(dst, counts,
        W_in, W_msg0, W_msg1, W_out, wih0, whh0, wih1, whh1,
        pWin, pWm0, pWm1, pWout, pI0, pH0, pI1, pH1);
    scan_partial_kernel<<<SCAN_BLOCKS, 256, 0, stream>>>(counts, partial);
    scan_base_kernel<<<1, 256, 0, stream>>>(partial, pbase);
    scan_final_kernel<<<SCAN_BLOCKS, 256, 0, stream>>>(counts, pbase, offsets, cursor);
    fill_part_kernel<<<NPART * FILL_CHUNKS, 256, 0, stream>>>(src, dst, cursor, perm);

    int g64 = (NN + 63) / 64;    // 782

    // h0 = relu(x@W_in+b) ; m0 = h0@W_msg0   (fused)
    fused_in_msg<<<g64, 256, 0, stream>>>(x, pWin, b_in, pWm0, bufA, bufB);

    // layer 0: agg0 ; {h1 = GRU(agg0,h0) ; m1 = h1@W_msg1} fused
    aggregate_bf16<<<(NN + 7) / 8, 256, 0, stream>>>(bufB, offsets, perm, bufC);
    fused_gru<8, false, true><<<g64, 256, 0, stream>>>(bufC, bufA, pI0, pH0, bih0, bhh0,
                                                       pWm1, nullptr, bufB, bufA);

    // layer 1: agg1 ; {h2 = GRU(agg1,h1) ; out = h2@W_out+b} fused, h2 stays in LDS
    aggregate_bf16<<<(NN + 7) / 8, 256, 0, stream>>>(bufA, offsets, perm, bufC);
    fused_gru<2, true, false><<<g64, 256, 0, stream>>>(bufC, bufB, pI1, pH1, bih1, bhh1,
                                                       pWout, b_out, nullptr, out);
}

// Round 15
// 341.771 us; speedup vs baseline: 1.1418x; 1.0540x over previous
//
#include <hip/hip_runtime.h>
#include <hip/hip_bf16.h>
#include <math.h>

#define NN 50000
#define NE 800000
#define HD 128
#define SCAN_BLOCKS 196   // 196 * 256 = 50176 >= NN
#define FILL_CHUNK 4096
#define FILL_CHUNKS ((NE + FILL_CHUNK - 1) / FILL_CHUNK)   // 196
#define NPART 8
#define HIST_BLOCKS ((NE + 255) / 256)   // 3125

typedef __attribute__((ext_vector_type(8))) short bf16x8;
typedef __attribute__((ext_vector_type(4))) float f32x4;

__device__ inline float b2f(unsigned short s) {
    union { unsigned int u; float f; } w; w.u = ((unsigned int)s) << 16; return w.f;
}
__device__ inline short f2b(float f) {
    __hip_bfloat16 h = __float2bfloat16(f);
    short s; __builtin_memcpy(&s, &h, 2); return s;
}

// ---------------- prep: hist + weight pack fused ----------------
__global__ void prep_kernel(const int* __restrict__ dst, int* __restrict__ counts,
                            const float* W_in, const float* W_msg0, const float* W_msg1,
                            const float* W_out, const float* wih0, const float* whh0,
                            const float* wih1, const float* whh1,
                            short* pWin, short* pWm0, short* pWm1, short* pWout,
                            short* pI0, short* pH0, short* pI1, short* pH1) {
    int b = blockIdx.x;
    if (b < HIST_BLOCKS) {
        int e = b * 256 + threadIdx.x;
        if (e < NE) atomicAdd(&counts[dst[e]], 1);
        return;
    }
    int pb = b - HIST_BLOCKS;
    int px = pb % 24, wsel = pb / 24;
    const float* src; short* dstp; int JT; bool kmajor; int J;
    switch (wsel) {
        case 0: src = W_in;   dstp = pWin;  JT = 8;  kmajor = true;  J = 128; break;
        case 1: src = W_msg0; dstp = pWm0;  JT = 8;  kmajor = true;  J = 128; break;
        case 2: src = W_msg1; dstp = pWm1;  JT = 8;  kmajor = true;  J = 128; break;
        case 3: src = W_out;  dstp = pWout; JT = 2;  kmajor = true;  J = 32;  break;
        case 4: src = wih0;   dstp = pI0;   JT = 24; kmajor = false; J = 384; break;
        case 5: src = whh0;   dstp = pH0;   JT = 24; kmajor = false; J = 384; break;
        case 6: src = wih1;   dstp = pI1;   JT = 24; kmajor = false; J = 384; break;
        default: src = whh1;  dstp = pH1;   JT = 24; kmajor = false; J = 384; break;
    }
    int t = px * 256 + threadIdx.x;
    if (t >= JT * 4 * 64) return;
    int l = t & 63, ks = (t >> 6) & 3, jt = t >> 8;
    int j = jt * 16 + (l & 15);
    int k0 = ks * 32 + (l >> 4) * 8;
    bf16x8 tv;
    if (kmajor) {
        #pragma unroll
        for (int i = 0; i < 8; ++i) tv[i] = f2b(src[(k0 + i) * J + j]);
    } else {
        #pragma unroll
        for (int i = 0; i < 8; ++i) tv[i] = f2b(src[j * 128 + k0 + i]);
    }
    *reinterpret_cast<bf16x8*>(dstp + t * 8) = tv;
}

// ---------------- scan (3-stage device-wide) ----------------
__global__ __launch_bounds__(256) void scan_partial_kernel(const int* __restrict__ counts,
                                                           int* __restrict__ partial) {
    __shared__ int sm[256];
    int i = blockIdx.x * 256 + threadIdx.x;
    sm[threadIdx.x] = (i < NN) ? counts[i] : 0;
    __syncthreads();
    for (int off = 128; off > 0; off >>= 1) {
        if (threadIdx.x < off) sm[threadIdx.x] += sm[threadIdx.x + off];
        __syncthreads();
    }
    if (threadIdx.x == 0) partial[blockIdx.x] = sm[0];
}

__global__ __launch_bounds__(256) void scan_base_kernel(const int* __restrict__ partial,
                                                        int* __restrict__ base) {
    __shared__ int sm[256];
    int tid = threadIdx.x;
    int v = (tid < SCAN_BLOCKS) ? partial[tid] : 0;
    sm[tid] = v;
    __syncthreads();
    for (int off = 1; off < 256; off <<= 1) {
        int t = (tid >= off) ? sm[tid - off] : 0;
        __syncthreads();
        sm[tid] += t;
        __syncthreads();
    }
    if (tid < SCAN_BLOCKS) base[tid] = sm[tid] - v;
}

__global__ __launch_bounds__(256) void scan_final_kernel(const int* __restrict__ counts,
                                                         const int* __restrict__ base,
                                                         int* __restrict__ offsets,
                                                         int* __restrict__ cursor) {
    __shared__ int sm[256];
    int tid = threadIdx.x;
    int i = blockIdx.x * 256 + tid;
    int v = (i < NN) ? counts[i] : 0;
    sm[tid] = v;
    __syncthreads();
    for (int off = 1; off < 256; off <<= 1) {
        int t = (tid >= off) ? sm[tid - off] : 0;
        __syncthreads();
        sm[tid] += t;
        __syncthreads();
    }
    if (i < NN) {
        int o = base[blockIdx.x] + sm[tid] - v;
        offsets[i] = o;
        cursor[i]  = o;
        if (i == NN - 1) offsets[NN] = o + v;
    }
}

// XCD-partitioned fill (round-8 win)
__global__ __launch_bounds__(256) void fill_part_kernel(const int* __restrict__ src,
                                                        const int* __restrict__ dst,
                                                        int* __restrict__ cursor,
                                                        int* __restrict__ perm_src) {
    int part  = blockIdx.x & (NPART - 1);
    int chunk = blockIdx.x >> 3;
    int lo = part * (NN / NPART);
    int hi = (part == NPART - 1) ? NN : lo + (NN / NPART);
    int e0 = chunk * FILL_CHUNK;
    int e1 = min(e0 + FILL_CHUNK, NE);
    for (int e = e0 + threadIdx.x; e < e1; e += 256) {
        int d = dst[e];
        if (d >= lo && d < hi) {
            int pos = atomicAdd(&cursor[d], 1);
            perm_src[pos] = src[e];
        }
    }
}

// ---------------- CSR aggregate (bf16 in, fp32 accum, bf16 out) ----------------
__global__ __launch_bounds__(256) void aggregate_bf16(const short* __restrict__ m,
                                                      const int* __restrict__ offsets,
                                                      const int* __restrict__ perm_src,
                                                      short* __restrict__ agg) {
    int node = blockIdx.x * 8 + (threadIdx.x >> 5);
    if (node >= NN) return;
    int q = (threadIdx.x & 31) * 4;
    int beg = offsets[node], end = offsets[node + 1];
    float a0 = 0.f, a1 = 0.f, a2 = 0.f, a3 = 0.f;
    int e = beg;
    for (; e + 2 <= end; e += 2) {
        int s0 = perm_src[e], s1 = perm_src[e + 1];
        ushort4 u0 = *reinterpret_cast<const ushort4*>(m + (size_t)s0 * HD + q);
        ushort4 u1 = *reinterpret_cast<const ushort4*>(m + (size_t)s1 * HD + q);
        a0 += b2f(u0.x) + b2f(u1.x);
        a1 += b2f(u0.y) + b2f(u1.y);
        a2 += b2f(u0.z) + b2f(u1.z);
        a3 += b2f(u0.w) + b2f(u1.w);
    }
    if (e < end) {
        ushort4 u = *reinterpret_cast<const ushort4*>(m + (size_t)perm_src[e] * HD + q);
        a0 += b2f(u.x); a1 += b2f(u.y); a2 += b2f(u.z); a3 += b2f(u.w);
    }
    ushort4 o;
    o.x = (unsigned short)f2b(a0); o.y = (unsigned short)f2b(a1);
    o.z = (unsigned short)f2b(a2); o.w = (unsigned short)f2b(a3);
    *reinterpret_cast<ushort4*>(agg + (size_t)node * HD + q) = o;
}

// ---------------- shared phase-2: C2 = hLDS @ Bp2 (+bias2) ----------------
template<int JT2, bool OUTF32_2>
__device__ inline void second_gemm(const short* hw, int l, int r0,
                                   const short* __restrict__ Bp2,
                                   const float* __restrict__ bias2,
                                   void* __restrict__ Cv2) {
    int lr = l & 15;
    bf16x8 a2[4];
    #pragma unroll
    for (int ks = 0; ks < 4; ++ks) {
        int row = l & 15;
        int col = (ks * 32 + (l >> 4) * 8) ^ ((row & 7) << 3);
        a2[ks] = *reinterpret_cast<const bf16x8*>(hw + row * 128 + col);
    }
    const f32x4 zero = {0.f, 0.f, 0.f, 0.f};
    #pragma unroll
    for (int jt = 0; jt < JT2; ++jt) {
        f32x4 acc = zero;
        const short* bp = Bp2 + ((jt * 4) * 64 + l) * 8;
        #pragma unroll
        for (int ks = 0; ks < 4; ++ks) {
            bf16x8 b = *reinterpret_cast<const bf16x8*>(bp + ks * 64 * 8);
            acc = __builtin_amdgcn_mfma_f32_16x16x32_bf16(a2[ks], b, acc, 0, 0, 0);
        }
        int col = jt * 16 + lr;
        float bs = bias2 ? bias2[col] : 0.f;
        #pragma unroll
        for (int rg = 0; rg < 4; ++rg) {
            int row = r0 + (l >> 4) * 4 + rg;
            if (row < NN) {
                float v = acc[rg] + bs;
                if (OUTF32_2) ((float*)Cv2)[(size_t)row * (16 * JT2) + col] = v;
                else          ((short*)Cv2)[(size_t)row * (16 * JT2) + col] = f2b(v);
            }
        }
    }
}

// ---------------- fused: h0 = relu(x @ W_in + b), m0 = h0 @ W_msg0 ----------------
__global__ __launch_bounds__(256) void fused_in_msg(const float* __restrict__ x,
                                                    const short* __restrict__ Bp1,
                                                    const float* __restrict__ bias1,
                                                    const short* __restrict__ Bp2,
                                                    short* __restrict__ Hout,
                                                    short* __restrict__ Mout) {
    __shared__ short hl[4][2048];
    int w = threadIdx.x >> 6, l = threadIdx.x & 63;
    int r0 = blockIdx.x * 64 + w * 16;
    int lr = l & 15, lk = (l >> 4) * 8;
    short* hw = hl[w];

    bf16x8 a[4];
    {
        int row = min(r0 + lr, NN - 1);
        #pragma unroll
        for (int ks = 0; ks < 4; ++ks) {
            const float* ap = x + (size_t)row * HD + ks * 32 + lk;
            float4 v0 = *(const float4*)ap;
            float4 v1 = *(const float4*)(ap + 4);
            bf16x8 tv;
            tv[0] = f2b(v0.x); tv[1] = f2b(v0.y); tv[2] = f2b(v0.z); tv[3] = f2b(v0.w);
            tv[4] = f2b(v1.x); tv[5] = f2b(v1.y); tv[6] = f2b(v1.z); tv[7] = f2b(v1.w);
            a[ks] = tv;
        }
    }

    const f32x4 zero = {0.f, 0.f, 0.f, 0.f};
    #pragma unroll
    for (int jt = 0; jt < 8; ++jt) {
        f32x4 acc = zero;
        const short* bp = Bp1 + ((jt * 4) * 64 + l) * 8;
        #pragma unroll
        for (int ks = 0; ks < 4; ++ks) {
            bf16x8 b = *reinterpret_cast<const bf16x8*>(bp + ks * 64 * 8);
            acc = __builtin_amdgcn_mfma_f32_16x16x32_bf16(a[ks], b, acc, 0, 0, 0);
        }
        int col = jt * 16 + lr;
        float bs = bias1[col];
        #pragma unroll
        for (int rg = 0; rg < 4; ++rg) {
            int row16 = (l >> 4) * 4 + rg;
            int grow = r0 + row16;
            float v = fmaxf(acc[rg] + bs, 0.f);
            short hb = f2b(v);
            hw[row16 * 128 + (col ^ ((row16 & 7) << 3))] = hb;
            if (grow < NN) Hout[(size_t)grow * HD + col] = hb;
        }
    }
    __syncthreads();
    second_gemm<8, false>(hw, l, r0, Bp2, nullptr, Mout);
}

// ---------------- fused GRU + second GEMM, with cooperative LDS weight staging ----------------
// Per jt: block stages 24KB (2src x 3gate x 4ks x 1KB chunks) into LDS; 4 waves share.
// Next-jt global loads issued before compute so L2 latency hides under MFMA+epilogue.
template<int JT2, bool OUTF32_2, bool WRITE_H>
__global__ __launch_bounds__(256) void fused_gru(const short* __restrict__ agg,
                                                 const short* __restrict__ h,
                                                 const short* __restrict__ BpI,
                                                 const short* __restrict__ BpH,
                                                 const float* __restrict__ bih,
                                                 const float* __restrict__ bhh,
                                                 const short* __restrict__ Bp2,
                                                 const float* __restrict__ bias2,
                                                 short* __restrict__ Hout,
                                                 void* __restrict__ Cv2) {
    __shared__ short hl[4][2048];   // 16KB h'-tiles (per-wave, swizzled)
    __shared__ short bw[24 * 512];  // 24KB weight staging (one jt slice)
    int w = threadIdx.x >> 6, l = threadIdx.x & 63;
    int r0 = blockIdx.x * 64 + w * 16;
    int lr = l & 15, lk = (l >> 4) * 8;
    short* hw = hl[w];

    bf16x8 aa[4], ah[4];
    {
        int row = min(r0 + lr, NN - 1);
        #pragma unroll
        for (int ks = 0; ks < 4; ++ks) {
            aa[ks] = *reinterpret_cast<const bf16x8*>(agg + (size_t)row * HD + ks * 32 + lk);
            ah[ks] = *reinterpret_cast<const bf16x8*>(h   + (size_t)row * HD + ks * 32 + lk);
        }
    }

    // staged chunks: c = w + 4*i, c in [0,24): c = src*12 + gate*4 + ks
    bf16x8 streg[6];
    auto stage_regs = [&](int jt) {
        #pragma unroll
        for (int i = 0; i < 6; ++i) {
            int c = w + 4 * i;
            int s = c / 12, rem = c % 12, g = rem >> 2, ks = rem & 3;
            const short* p = (s ? BpH : BpI) + g * (8 * 4 * 64 * 8) + ((jt * 4 + ks) * 64 + l) * 8;
            streg[i] = *reinterpret_cast<const bf16x8*>(p);
        }
    };
    auto write_lds = [&]() {
        #pragma unroll
        for (int i = 0; i < 6; ++i) {
            int c = w + 4 * i;
            *reinterpret_cast<bf16x8*>(&bw[c * 512 + l * 8]) = streg[i];
        }
    };

    stage_regs(0);
    const f32x4 zero = {0.f, 0.f, 0.f, 0.f};
    #pragma unroll 1
    for (int jt = 0; jt < 8; ++jt) {
        __syncthreads();            // all waves done reading previous jt slice
        write_lds();
        if (jt < 7) stage_regs(jt + 1);   // global loads in flight during compute
        __syncthreads();            // staged slice visible

        f32x4 ir = zero, iz = zero, in_ = zero;
        f32x4 hr = zero, hz = zero, hn = zero;
        #pragma unroll
        for (int ks = 0; ks < 4; ++ks) {
            bf16x8 bir = *reinterpret_cast<const bf16x8*>(&bw[(0 * 12 + 0 * 4 + ks) * 512 + l * 8]);
            bf16x8 biz = *reinterpret_cast<const bf16x8*>(&bw[(0 * 12 + 1 * 4 + ks) * 512 + l * 8]);
            bf16x8 bin = *reinterpret_cast<const bf16x8*>(&bw[(0 * 12 + 2 * 4 + ks) * 512 + l * 8]);
            bf16x8 bhr = *reinterpret_cast<const bf16x8*>(&bw[(1 * 12 + 0 * 4 + ks) * 512 + l * 8]);
            bf16x8 bhz = *reinterpret_cast<const bf16x8*>(&bw[(1 * 12 + 1 * 4 + ks) * 512 + l * 8]);
            bf16x8 bhn = *reinterpret_cast<const bf16x8*>(&bw[(1 * 12 + 2 * 4 + ks) * 512 + l * 8]);
            ir  = __builtin_amdgcn_mfma_f32_16x16x32_bf16(aa[ks], bir, ir,  0, 0, 0);
            iz  = __builtin_amdgcn_mfma_f32_16x16x32_bf16(aa[ks], biz, iz,  0, 0, 0);
            in_ = __builtin_amdgcn_mfma_f32_16x16x32_bf16(aa[ks], bin, in_, 0, 0, 0);
            hr  = __builtin_amdgcn_mfma_f32_16x16x32_bf16(ah[ks], bhr, hr,  0, 0, 0);
            hz  = __builtin_amdgcn_mfma_f32_16x16x32_bf16(ah[ks], bhz, hz,  0, 0, 0);
            hn  = __builtin_amdgcn_mfma_f32_16x16x32_bf16(ah[ks], bhn, hn,  0, 0, 0);
        }
        int col = jt * 16 + lr;
        float bir_ = bih[col], biz_ = bih[128 + col], bin_ = bih[256 + col];
        float bhr_ = bhh[col], bhz_ = bhh[128 + col], bhn_ = bhh[256 + col];
        #pragma unroll
        for (int rg = 0; rg < 4; ++rg) {
            int row16 = (l >> 4) * 4 + rg;
            int grow = r0 + row16;
            int crow = min(grow, NN - 1);
            float rr = 1.f / (1.f + __expf(-(ir[rg] + bir_ + hr[rg] + bhr_)));
            float zz = 1.f / (1.f + __expf(-(iz[rg] + biz_ + hz[rg] + bhz_)));
            float pre = in_[rg] + bin_ + rr * (hn[rg] + bhn_);
            pre = fminf(fmaxf(pre, -20.f), 20.f);
            float e2 = __expf(2.f * pre);
            float nn_ = (e2 - 1.f) / (e2 + 1.f);
            float hv = b2f((unsigned short)h[(size_t)crow * HD + col]);
            float nh = (1.f - zz) * nn_ + zz * hv;
            short hb = f2b(nh);
            hw[row16 * 128 + (col ^ ((row16 & 7) << 3))] = hb;
            if (WRITE_H && grow < NN) Hout[(size_t)grow * HD + col] = hb;
        }
    }
    __syncthreads();
    second_gemm<JT2, OUTF32_2>(hw, l, r0, Bp2, bias2, Cv2);
}

// ---------------- launch ----------------
extern "C" void kernel_launch(void* const* d_in, const int* in_sizes, int n_in,
                              void* d_out, int out_size, void* d_ws, size_t ws_size,
                              hipStream_t stream) {
    const float* x      = (const float*)d_in[0];
    const int*   eidx   = (const int*)d_in[1];
    const float* W_in   = (const float*)d_in[2];
    const float* b_in   = (const float*)d_in[3];
    const float* W_msg0 = (const float*)d_in[4];
    const float* wih0   = (const float*)d_in[5];
    const float* whh0   = (const float*)d_in[6];
    const float* bih0   = (const float*)d_in[7];
    const float* bhh0   = (const float*)d_in[8];
    const float* W_msg1 = (const float*)d_in[9];
    const float* wih1   = (const float*)d_in[10];
    const float* whh1   = (const float*)d_in[11];
    const float* bih1   = (const float*)d_in[12];
    const float* bhh1   = (const float*)d_in[13];
    const float* W_out  = (const float*)d_in[14];
    const float* b_out  = (const float*)d_in[15];
    float* out = (float*)d_out;

    const int* src = eidx;
    const int* dst = eidx + NE;

    char* ws = (char*)d_ws;
    size_t off = 0;
    auto alloc = [&](size_t bytes) {
        void* p = ws + off;
        off += (bytes + 255) & ~(size_t)255;
        return p;
    };
    short* bufA = (short*)alloc((size_t)NN * HD * 2);   // h0, then m1
    short* bufB = (short*)alloc((size_t)NN * HD * 2);   // m0, then h1
    short* bufC = (short*)alloc((size_t)NN * HD * 2);   // agg0 / agg1
    short* pWin  = (short*)alloc(8  * 4 * 64 * 8 * 2);
    short* pWm0  = (short*)alloc(8  * 4 * 64 * 8 * 2);
    short* pWm1  = (short*)alloc(8  * 4 * 64 * 8 * 2);
    short* pWout = (short*)alloc(2  * 4 * 64 * 8 * 2);
    short* pI0   = (short*)alloc(24 * 4 * 64 * 8 * 2);
    short* pH0   = (short*)alloc(24 * 4 * 64 * 8 * 2);
    short* pI1   = (short*)alloc(24 * 4 * 64 * 8 * 2);
    short* pH1   = (short*)alloc(24 * 4 * 64 * 8 * 2);
    int* counts  = (int*)alloc(NN * 4);
    int* offsets = (int*)alloc((NN + 1) * 4);
    int* cursor  = (int*)alloc(NN * 4);
    int* perm    = (int*)alloc(NE * 4);
    int* partial = (int*)alloc(SCAN_BLOCKS * 4);
    int* pbase   = (int*)alloc(SCAN_BLOCKS * 4);

    // CSR build + weight pack
    hipMemsetAsync(counts, 0, NN * 4, stream);
    prep_kernel<<<HIST_BLOCKS + 192, 256, 0, stream>>>(dst, counts,
        W_in, W_msg0, W_msg1, W_out, wih0, whh0, wih1, whh1,
        pWin, pWm0, pWm1, pWout, pI0, pH0, pI1, pH1);
    scan_partial_kernel<<<SCAN_BLOCKS, 256, 0, stream>>>(counts, partial);
    scan_base_kernel<<<1, 256, 0, stream>>>(partial, pbase);
    scan_final_kernel<<<SCAN_BLOCKS, 256, 0, stream>>>(counts, pbase, offsets, cursor);
    fill_part_kernel<<<NPART * FILL_CHUNKS, 256, 0, stream>>>(src, dst, cursor, perm);

    int g64 = (NN + 63) / 64;    // 782

    // h0 = relu(x@W_in+b) ; m0 = h0@W_msg0   (fused)
    fused_in_msg<<<g64, 256, 0, stream>>>(x, pWin, b_in, pWm0, bufA, bufB);

    // layer 0: agg0 ; {h1 = GRU(agg0,h0) ; m1 = h1@W_msg1} fused
    aggregate_bf16<<<(NN + 7) / 8, 256, 0, stream>>>(bufB, offsets, perm, bufC);
    fused_gru<8, false, true><<<g64, 256, 0, stream>>>(bufC, bufA, pI0, pH0, bih0, bhh0,
                                                       pWm1, nullptr, bufB, bufA);

    // layer 1: agg1 ; {h2 = GRU(agg1,h1) ; out = h2@W_out+b} fused, h2 stays in LDS
    aggregate_bf16<<<(NN + 7) / 8, 256, 0, stream>>>(bufA, offsets, perm, bufC);
    fused_gru<2, true, false><<<g64, 256, 0, stream>>>(bufC, bufB, pI1, pH1, bih1, bhh1,
                                                       pWout, b_out, nullptr, out);
}